// Round 1
// baseline (11306.423 us; speedup 1.0000x reference)
//
#include <hip/hip_runtime.h>
#include <hip/hip_bf16.h>
#include <hip/hip_cooperative_groups.h>

namespace cg = cooperative_groups;

typedef __bf16 bf16x8 __attribute__((ext_vector_type(8)));
typedef float floatx4 __attribute__((ext_vector_type(4)));

#define B_ 16
#define N_ 512
#define I_ 512
#define H_ 1024

// workspace byte offsets
constexpr size_t OFF_TT  = 0;                               // Tt bf16: 3 * H*H * 2 = 6 MB
constexpr size_t OFF_V   = OFF_TT + 3ull * H_ * H_ * 2;     // V bf16:  3 * H*H * 2 = 6 MB
constexpr size_t OFF_F0  = OFF_V + 3ull * H_ * H_ * 2;      // f0,o0,z0 fp32: 3 * B*H * 4
constexpr size_t OFF_C   = OFF_F0 + 3ull * B_ * H_ * 4;     // tree_c fp32: B*N*H*4 = 32 MB
constexpr size_t OFF_HBF = OFF_C + (size_t)B_ * N_ * H_ * 4;// h bf16 shadow: B*N*H*2 = 16 MB
// total = 63,111,168 bytes

// ---------------------------------------------------------------------------
// Kernel 1: Tt[g][j][k] = bf16(T_g[k][j])  (transpose so MFMA frags read rows)
// ---------------------------------------------------------------------------
__global__ void __launch_bounds__(256)
t_transpose(const float* __restrict__ Tf, const float* __restrict__ To,
            const float* __restrict__ Tz, char* __restrict__ ws)
{
    __shared__ float tile[64][65];
    int g   = blockIdx.x >> 8;
    int rem = blockIdx.x & 255;
    int tj = rem >> 4, tk = rem & 15;
    const float* T = (g == 0) ? Tf : (g == 1) ? To : Tz;
    int c  = threadIdx.x & 63;
    int r0 = threadIdx.x >> 6;
#pragma unroll
    for (int l = 0; l < 16; ++l) {
        int r = l * 4 + r0;
        tile[r][c] = T[(size_t)(tk * 64 + r) * H_ + tj * 64 + c];
    }
    __syncthreads();
    __hip_bfloat16* Tt = (__hip_bfloat16*)(ws + OFF_TT) + (size_t)g * H_ * H_;
#pragma unroll
    for (int l = 0; l < 16; ++l) {
        int rr = l * 4 + r0;
        Tt[(size_t)(tj * 64 + rr) * H_ + tk * 64 + c] = __float2bfloat16(tile[c][rr]);
    }
}

// ---------------------------------------------------------------------------
// Kernel 2: root node -- f0/o0/z0 = x0 @ W + b ; root h,c ; bf16 h shadow
// grid: 64 blocks (b = blk>>2, h = (blk&3)*256 + tid)
// ---------------------------------------------------------------------------
__global__ void __launch_bounds__(256)
k0_root(const float* __restrict__ te,
        const float* __restrict__ Wf, const float* __restrict__ bfv,
        const float* __restrict__ Wo, const float* __restrict__ bov,
        const float* __restrict__ Wz, const float* __restrict__ bzv,
        float* __restrict__ out, char* __restrict__ ws)
{
    __shared__ float x0[I_];
    int b = blockIdx.x >> 2;
    int h = ((blockIdx.x & 3) << 8) + threadIdx.x;
    for (int k = threadIdx.x; k < I_; k += 256)
        x0[k] = te[(size_t)b * N_ * I_ + k];
    __syncthreads();
    float af = bfv[h], ao = bov[h], az = bzv[h];
#pragma unroll 4
    for (int k = 0; k < I_; ++k) {
        float x = x0[k];
        af = fmaf(x, Wf[k * H_ + h], af);
        ao = fmaf(x, Wo[k * H_ + h], ao);
        az = fmaf(x, Wz[k * H_ + h], az);
    }
    float* f0 = (float*)(ws + OFF_F0);
    f0[b * H_ + h]               = af;
    f0[B_ * H_ + b * H_ + h]     = ao;
    f0[2 * B_ * H_ + b * H_ + h] = az;
    float f = 1.0f / (1.0f + __expf(-af));
    float o = 1.0f / (1.0f + __expf(-ao));
    float z = tanhf(az);
    float c = z * (1.0f - f);
    float hh = o * tanhf(c);
    size_t idx = (size_t)b * N_ * H_ + h;   // node 0
    ((float*)(ws + OFF_C))[idx] = c;
    out[idx] = hh;
    ((__hip_bfloat16*)(ws + OFF_HBF))[idx] = __float2bfloat16(hh);
}

// ---------------------------------------------------------------------------
// Kernel 3: V_g = Tt_g · Tt_g^T  (== T^T T), bf16 MFMA, one 16x16 tile/wave
// grid: 3072 blocks * 256 thr = 12288 waves = 3 gates * 64*64 tiles
// ---------------------------------------------------------------------------
__global__ void __launch_bounds__(256)
v_gemm(char* __restrict__ ws)
{
    int wv  = (blockIdx.x << 2) + (threadIdx.x >> 6);
    int g   = wv >> 12;
    int rem = wv & 4095;
    int mt = rem >> 6, ntt = rem & 63;
    int lane = threadIdx.x & 63;
    int q = lane >> 4, m = lane & 15;
    const __bf16* Tt = (const __bf16*)(ws + OFF_TT) + (size_t)g * H_ * H_;
    const __bf16* pA = Tt + (size_t)(mt * 16 + m) * H_ + q * 8;
    const __bf16* pB = Tt + (size_t)(ntt * 16 + m) * H_ + q * 8;
    floatx4 acc0 = {0.f, 0.f, 0.f, 0.f}, acc1 = {0.f, 0.f, 0.f, 0.f};
#pragma unroll 4
    for (int c = 0; c < 32; c += 2) {
        bf16x8 a0 = *(const bf16x8*)(pA + c * 32);
        bf16x8 b0 = *(const bf16x8*)(pB + c * 32);
        bf16x8 a1 = *(const bf16x8*)(pA + c * 32 + 32);
        bf16x8 b1 = *(const bf16x8*)(pB + c * 32 + 32);
        acc0 = __builtin_amdgcn_mfma_f32_16x16x32_bf16(a0, b0, acc0, 0, 0, 0);
        acc1 = __builtin_amdgcn_mfma_f32_16x16x32_bf16(a1, b1, acc1, 0, 0, 0);
    }
    floatx4 acc = acc0 + acc1;
    __hip_bfloat16* V = (__hip_bfloat16*)(ws + OFF_V) + (size_t)g * H_ * H_;
#pragma unroll
    for (int r = 0; r < 4; ++r)
        V[(size_t)(mt * 16 + q * 4 + r) * H_ + ntt * 16 + m] = __float2bfloat16(acc[r]);
}

// ---------------------------------------------------------------------------
// Kernel 4: the sequential scan. Cooperative, 64 WGs (one per 16-col tile).
// waves 0..2 = gates f,o,z : C[b][n] = sum_k h[b][parent_b][k] * V_g[k][hcol]
//   A-frag: lane m = batch, gathered from bf16 h shadow (16B/lane)
//   B-frag: V row (symmetric!) read k-contiguous (16B/lane)
// epilogue: 256 thr = 16b x 16n, fp32 LSTM cell, write h/c, grid sync.
// ---------------------------------------------------------------------------
__global__ void __launch_bounds__(256)
scan_kernel(const int* __restrict__ conn, float* __restrict__ out,
            char* __restrict__ ws)
{
    __shared__ int conn_t[N_ * B_];       // [i][b] transposed for bank spread
    __shared__ float ldsC[3][16][17];

    const int t    = threadIdx.x;
    const int wave = t >> 6;
    const int lane = t & 63;
    const int q = lane >> 4;
    const int m = lane & 15;
    const int nt = blockIdx.x;            // 64 tiles of 16 columns

    for (int idx = t; idx < N_ * B_; idx += 256) {
        int b = idx >> 9;                 // N_=512
        int i = idx & (N_ - 1);
        conn_t[i * B_ + b] = conn[idx];
    }
    __syncthreads();

    const __bf16* __restrict__ Vbf = (const __bf16*)(ws + OFF_V);
    const __bf16* __restrict__ hb  = (const __bf16*)(ws + OFF_HBF);
    __hip_bfloat16* __restrict__ hbs = (__hip_bfloat16*)(ws + OFF_HBF);
    const float* __restrict__ f0 = (const float*)(ws + OFF_F0);
    const float* __restrict__ o0 = f0 + B_ * H_;
    const float* __restrict__ z0 = o0 + B_ * H_;
    float* __restrict__ tc = (float*)(ws + OFF_C);

    // per-lane B pointer: row (nt*16+m) of V_gate (V symmetric -> row == col)
    const __bf16* pB0 = Vbf + (size_t)(wave < 3 ? wave : 0) * H_ * H_
                            + (size_t)(nt * 16 + m) * H_ + q * 8;

    cg::grid_group grid = cg::this_grid();

    for (int i = 1; i < N_; ++i) {
        if (wave < 3) {
            int p = conn_t[i * B_ + m];   // parent of batch m
            const __bf16* pA = hb + ((size_t)(m * N_ + p)) * H_ + q * 8;
            floatx4 acc0 = {0.f, 0.f, 0.f, 0.f}, acc1 = {0.f, 0.f, 0.f, 0.f};
#pragma unroll 4
            for (int c = 0; c < 32; c += 2) {
                bf16x8 a0 = *(const bf16x8*)(pA + c * 32);
                bf16x8 b0 = *(const bf16x8*)(pB0 + c * 32);
                bf16x8 a1 = *(const bf16x8*)(pA + c * 32 + 32);
                bf16x8 b1 = *(const bf16x8*)(pB0 + c * 32 + 32);
                acc0 = __builtin_amdgcn_mfma_f32_16x16x32_bf16(a0, b0, acc0, 0, 0, 0);
                acc1 = __builtin_amdgcn_mfma_f32_16x16x32_bf16(a1, b1, acc1, 0, 0, 0);
            }
            floatx4 acc = acc0 + acc1;
#pragma unroll
            for (int r = 0; r < 4; ++r)
                ldsC[wave][q * 4 + r][m] = acc[r];   // row=b (quad*4+reg), col=n
        }
        __syncthreads();
        {
            int b = t >> 4, n = t & 15;
            int hcol = nt * 16 + n;
            int p = conn_t[i * B_ + b];
            size_t idxP = ((size_t)(b * N_ + p)) * H_ + hcol;
            size_t idxI = ((size_t)(b * N_ + i)) * H_ + hcol;
            float af = ldsC[0][b][n] + f0[b * H_ + hcol];
            float ao = ldsC[1][b][n] + o0[b * H_ + hcol];
            float az = ldsC[2][b][n] + z0[b * H_ + hcol];
            float f = 1.0f / (1.0f + __expf(-af));
            float o = 1.0f / (1.0f + __expf(-ao));
            float z = tanhf(az);
            float pc = tc[idxP];
            float cc = pc * f + z * (1.0f - f);
            float hh = o * tanhf(cc);
            tc[idxI]  = cc;
            out[idxI] = hh;
            hbs[idxI] = __float2bfloat16(hh);
        }
        __threadfence();
        grid.sync();
    }
}

// ---------------------------------------------------------------------------
extern "C" void kernel_launch(void* const* d_in, const int* in_sizes, int n_in,
                              void* d_out, int out_size, void* d_ws, size_t ws_size,
                              hipStream_t stream)
{
    const float* te  = (const float*)d_in[0];
    const int*  conn = (const int*)d_in[1];
    // d_in[2] = node_mask (all ones, unused by reference path)
    const float* Wf = (const float*)d_in[3];
    const float* bf = (const float*)d_in[4];
    const float* Wo = (const float*)d_in[5];
    const float* bo = (const float*)d_in[6];
    const float* Wz = (const float*)d_in[7];
    const float* bz = (const float*)d_in[8];
    const float* Tf = (const float*)d_in[9];
    const float* To = (const float*)d_in[10];
    const float* Tz = (const float*)d_in[11];
    float* out = (float*)d_out;
    char*  ws  = (char*)d_ws;

    t_transpose<<<dim3(768), dim3(256), 0, stream>>>(Tf, To, Tz, ws);
    k0_root<<<dim3(64), dim3(256), 0, stream>>>(te, Wf, bf, Wo, bo, Wz, bz, out, ws);
    v_gemm<<<dim3(3072), dim3(256), 0, stream>>>(ws);

    void* args[] = { (void*)&conn, (void*)&out, (void*)&ws };
    hipLaunchCooperativeKernel((const void*)scan_kernel, dim3(64), dim3(256),
                               (void**)args, 0, stream);
}

// Round 2
// 4315.622 us; speedup vs baseline: 2.6199x; 2.6199x over previous
//
#include <hip/hip_runtime.h>
#include <hip/hip_bf16.h>

typedef __bf16 bf16x8 __attribute__((ext_vector_type(8)));
typedef float floatx4 __attribute__((ext_vector_type(4)));
typedef unsigned long long ull;

#define B_ 16
#define N_ 512
#define I_ 512
#define H_ 1024

// workspace byte offsets
constexpr size_t OFF_TT  = 0;                               // Tt bf16 (dead after v_gemm; barrier counter reuses byte 0)
constexpr size_t OFF_V   = OFF_TT + 3ull * H_ * H_ * 2;     // V bf16
constexpr size_t OFF_F0  = OFF_V + 3ull * H_ * H_ * 2;      // f0,o0,z0 fp32
constexpr size_t OFF_C   = OFF_F0 + 3ull * B_ * H_ * 4;     // tree_c fp32 (WG-column-private -> plain cached)
constexpr size_t OFF_HBF = OFF_C + (size_t)B_ * N_ * H_ * 4;// h bf16 shadow (cross-WG -> sc1 only)

// dynamic LDS layout for scan_kernel
constexpr int    VPITCH  = 1032;                            // 1024 + 8 pad: lane stride 516 dw -> 2-way bank alias (free)
constexpr size_t L_V     = 0;                               // 3*16*1032*2 = 99072
constexpr size_t L_CONN  = 99072;                           // 512*16*4    = 32768
constexpr size_t L_C     = 131840;                          // 3*16*17*4   = 3264
constexpr size_t L_H     = 135104;                          // 16*16*2     = 512
constexpr size_t L_TOTAL = 135616;

// ---------------------------------------------------------------------------
// Kernel 1: Tt[g][j][k] = bf16(T_g[k][j])
// ---------------------------------------------------------------------------
__global__ void __launch_bounds__(256)
t_transpose(const float* __restrict__ Tf, const float* __restrict__ To,
            const float* __restrict__ Tz, char* __restrict__ ws)
{
    __shared__ float tile[64][65];
    int g   = blockIdx.x >> 8;
    int rem = blockIdx.x & 255;
    int tj = rem >> 4, tk = rem & 15;
    const float* T = (g == 0) ? Tf : (g == 1) ? To : Tz;
    int c  = threadIdx.x & 63;
    int r0 = threadIdx.x >> 6;
#pragma unroll
    for (int l = 0; l < 16; ++l) {
        int r = l * 4 + r0;
        tile[r][c] = T[(size_t)(tk * 64 + r) * H_ + tj * 64 + c];
    }
    __syncthreads();
    __hip_bfloat16* Tt = (__hip_bfloat16*)(ws + OFF_TT) + (size_t)g * H_ * H_;
#pragma unroll
    for (int l = 0; l < 16; ++l) {
        int rr = l * 4 + r0;
        Tt[(size_t)(tj * 64 + rr) * H_ + tk * 64 + c] = __float2bfloat16(tile[c][rr]);
    }
}

// ---------------------------------------------------------------------------
// Kernel 2: root node -- f0/o0/z0 = x0 @ W + b ; root h,c ; bf16 h shadow
// ---------------------------------------------------------------------------
__global__ void __launch_bounds__(256)
k0_root(const float* __restrict__ te,
        const float* __restrict__ Wf, const float* __restrict__ bfv,
        const float* __restrict__ Wo, const float* __restrict__ bov,
        const float* __restrict__ Wz, const float* __restrict__ bzv,
        float* __restrict__ out, char* __restrict__ ws)
{
    __shared__ float x0[I_];
    int b = blockIdx.x >> 2;
    int h = ((blockIdx.x & 3) << 8) + threadIdx.x;
    for (int k = threadIdx.x; k < I_; k += 256)
        x0[k] = te[(size_t)b * N_ * I_ + k];
    __syncthreads();
    float af = bfv[h], ao = bov[h], az = bzv[h];
#pragma unroll 4
    for (int k = 0; k < I_; ++k) {
        float x = x0[k];
        af = fmaf(x, Wf[k * H_ + h], af);
        ao = fmaf(x, Wo[k * H_ + h], ao);
        az = fmaf(x, Wz[k * H_ + h], az);
    }
    float* f0 = (float*)(ws + OFF_F0);
    f0[b * H_ + h]               = af;
    f0[B_ * H_ + b * H_ + h]     = ao;
    f0[2 * B_ * H_ + b * H_ + h] = az;
    float f = 1.0f / (1.0f + __expf(-af));
    float o = 1.0f / (1.0f + __expf(-ao));
    float z = tanhf(az);
    float c = z * (1.0f - f);
    float hh = o * tanhf(c);
    size_t idx = (size_t)b * N_ * H_ + h;   // node 0
    ((float*)(ws + OFF_C))[idx] = c;
    out[idx] = hh;
    ((__hip_bfloat16*)(ws + OFF_HBF))[idx] = __float2bfloat16(hh);
}

// ---------------------------------------------------------------------------
// Kernel 3: V_g = Tt_g · Tt_g^T  (== T^T T), bf16 MFMA
// ---------------------------------------------------------------------------
__global__ void __launch_bounds__(256)
v_gemm(char* __restrict__ ws)
{
    int wv  = (blockIdx.x << 2) + (threadIdx.x >> 6);
    int g   = wv >> 12;
    int rem = wv & 4095;
    int mt = rem >> 6, ntt = rem & 63;
    int lane = threadIdx.x & 63;
    int q = lane >> 4, m = lane & 15;
    const __bf16* Tt = (const __bf16*)(ws + OFF_TT) + (size_t)g * H_ * H_;
    const __bf16* pA = Tt + (size_t)(mt * 16 + m) * H_ + q * 8;
    const __bf16* pB = Tt + (size_t)(ntt * 16 + m) * H_ + q * 8;
    floatx4 acc0 = {0.f, 0.f, 0.f, 0.f}, acc1 = {0.f, 0.f, 0.f, 0.f};
#pragma unroll 4
    for (int c = 0; c < 32; c += 2) {
        bf16x8 a0 = *(const bf16x8*)(pA + c * 32);
        bf16x8 b0 = *(const bf16x8*)(pB + c * 32);
        bf16x8 a1 = *(const bf16x8*)(pA + c * 32 + 32);
        bf16x8 b1 = *(const bf16x8*)(pB + c * 32 + 32);
        acc0 = __builtin_amdgcn_mfma_f32_16x16x32_bf16(a0, b0, acc0, 0, 0, 0);
        acc1 = __builtin_amdgcn_mfma_f32_16x16x32_bf16(a1, b1, acc1, 0, 0, 0);
    }
    floatx4 acc = acc0 + acc1;
    __hip_bfloat16* V = (__hip_bfloat16*)(ws + OFF_V) + (size_t)g * H_ * H_;
#pragma unroll
    for (int r = 0; r < 4; ++r)
        V[(size_t)(mt * 16 + q * 4 + r) * H_ + ntt * 16 + m] = __float2bfloat16(acc[r]);
}

// ---------------------------------------------------------------------------
// Kernel 3b: zero the scan barrier counter (lives in dead Tt region)
// ---------------------------------------------------------------------------
__global__ void bar_init(char* __restrict__ ws)
{
    *(unsigned*)(ws + OFF_TT) = 0u;
}

// ---------------------------------------------------------------------------
// Kernel 4: sequential scan. 64 WGs (16 columns each), V-slice in LDS,
// relaxed agent-scope atomic barrier (no L2 wb/inv per step).
// Cross-WG data (bf16 h shadow) moves ONLY via sc1 atomic load/store.
// ---------------------------------------------------------------------------
__global__ void __launch_bounds__(256)
scan_kernel(const int* __restrict__ conn, float* __restrict__ out,
            char* __restrict__ ws)
{
    extern __shared__ char lds[];
    __bf16*         ldsV   = (__bf16*)(lds + L_V);
    int*            conn_t = (int*)(lds + L_CONN);
    float*          ldsC   = (float*)(lds + L_C);
    __hip_bfloat16* ldsH   = (__hip_bfloat16*)(lds + L_H);

    const int t    = threadIdx.x;
    const int wave = t >> 6;
    const int lane = t & 63;
    const int q = lane >> 4;
    const int m = lane & 15;
    const int nt = blockIdx.x;            // 64 tiles of 16 columns

    // preload conn (transposed [i][b])
    for (int idx = t; idx < N_ * B_; idx += 256) {
        int b = idx >> 9;                 // N_=512
        int i = idx & (N_ - 1);
        conn_t[i * B_ + b] = conn[idx];
    }
    // preload V slice: rows nt*16..nt*16+15 of each gate (V symmetric)
    const __bf16* Vg = (const __bf16*)(ws + OFF_V);
    for (int j = t; j < 6144; j += 256) { // 6144 chunks of 8 bf16
        int g  = j >> 11;
        int rm = (j >> 7) & 15;
        int kk = (j & 127) << 3;
        bf16x8 v = *(const bf16x8*)(Vg + ((size_t)g << 20) + (size_t)(nt * 16 + rm) * H_ + kk);
        *(bf16x8*)(ldsV + (g * 16 + rm) * VPITCH + kk) = v;
    }
    __syncthreads();

    const ull*  hbu = (const ull*)(ws + OFF_HBF);
    ull*        hbw = (ull*)(ws + OFF_HBF);
    const float* __restrict__ f0 = (const float*)(ws + OFF_F0);
    const float* __restrict__ o0 = f0 + B_ * H_;
    const float* __restrict__ z0 = o0 + B_ * H_;
    float* __restrict__ tc = (float*)(ws + OFF_C);
    unsigned* bar = (unsigned*)(ws + OFF_TT);

    const __bf16* vB0 = ldsV + ((wave < 3 ? wave : 0) * 16 + m) * VPITCH + q * 8;

    for (int i = 1; i < N_; ++i) {
        if (wave < 3) {
            int p = conn_t[i * B_ + m];   // parent of batch m
            const ull* pA = hbu + (((size_t)(m * N_ + p) * H_) >> 2) + q * 2;
            floatx4 a0 = {0.f,0.f,0.f,0.f}, a1 = {0.f,0.f,0.f,0.f};
            floatx4 a2 = {0.f,0.f,0.f,0.f}, a3 = {0.f,0.f,0.f,0.f};
#pragma unroll 8
            for (int c = 0; c < 32; ++c) {
                union { ull u[2]; bf16x8 v; } ua;
                ua.u[0] = __hip_atomic_load(pA + (size_t)c * 8,     __ATOMIC_RELAXED, __HIP_MEMORY_SCOPE_AGENT);
                ua.u[1] = __hip_atomic_load(pA + (size_t)c * 8 + 1, __ATOMIC_RELAXED, __HIP_MEMORY_SCOPE_AGENT);
                bf16x8 bv = *(const bf16x8*)(vB0 + c * 32);
                switch (c & 3) {
                case 0:  a0 = __builtin_amdgcn_mfma_f32_16x16x32_bf16(ua.v, bv, a0, 0, 0, 0); break;
                case 1:  a1 = __builtin_amdgcn_mfma_f32_16x16x32_bf16(ua.v, bv, a1, 0, 0, 0); break;
                case 2:  a2 = __builtin_amdgcn_mfma_f32_16x16x32_bf16(ua.v, bv, a2, 0, 0, 0); break;
                default: a3 = __builtin_amdgcn_mfma_f32_16x16x32_bf16(ua.v, bv, a3, 0, 0, 0); break;
                }
            }
            floatx4 acc = (a0 + a1) + (a2 + a3);
#pragma unroll
            for (int r = 0; r < 4; ++r)
                ldsC[(wave * 16 + q * 4 + r) * 17 + m] = acc[r];  // row=b, col=n
        }
        __syncthreads();
        {
            int b = t >> 4, n = t & 15;
            int hcol = nt * 16 + n;
            int p = conn_t[i * B_ + b];
            size_t idxP = ((size_t)(b * N_ + p)) * H_ + hcol;
            size_t idxI = ((size_t)(b * N_ + i)) * H_ + hcol;
            float af = ldsC[(0 * 16 + b) * 17 + n] + f0[b * H_ + hcol];
            float ao = ldsC[(1 * 16 + b) * 17 + n] + o0[b * H_ + hcol];
            float az = ldsC[(2 * 16 + b) * 17 + n] + z0[b * H_ + hcol];
            float f = 1.0f / (1.0f + __expf(-af));
            float o = 1.0f / (1.0f + __expf(-ao));
            float z = tanhf(az);
            float pc = tc[idxP];          // WG-column-private -> plain cached load OK
            float cc = pc * f + z * (1.0f - f);
            float hh = o * tanhf(cc);
            tc[idxI]  = cc;
            out[idxI] = hh;
            ldsH[b * 16 + n] = __float2bfloat16(hh);
        }
        __syncthreads();
        if (t < 64) {                     // pack 4 bf16 -> one 8B sc1 store
            int bb = t >> 2, n4 = (t & 3) << 2;
            ull pack = *(const ull*)(ldsH + bb * 16 + n4);
            ull* dst = hbw + ((((size_t)(bb * N_ + i)) * H_ + nt * 16 + n4) >> 2);
            __hip_atomic_store(dst, pack, __ATOMIC_RELAXED, __HIP_MEMORY_SCOPE_AGENT);
        }
        __syncthreads();                  // drains vmcnt -> sc1 stores visible at MALL
        if (i < N_ - 1) {
            if (t == 0) {
                __hip_atomic_fetch_add(bar, 1u, __ATOMIC_RELAXED, __HIP_MEMORY_SCOPE_AGENT);
                unsigned tgt = 64u * (unsigned)i;
                while (__hip_atomic_load(bar, __ATOMIC_RELAXED, __HIP_MEMORY_SCOPE_AGENT) < tgt) {}
            }
            __syncthreads();
        }
    }
}

// ---------------------------------------------------------------------------
extern "C" void kernel_launch(void* const* d_in, const int* in_sizes, int n_in,
                              void* d_out, int out_size, void* d_ws, size_t ws_size,
                              hipStream_t stream)
{
    const float* te  = (const float*)d_in[0];
    const int*  conn = (const int*)d_in[1];
    const float* Wf = (const float*)d_in[3];
    const float* bf = (const float*)d_in[4];
    const float* Wo = (const float*)d_in[5];
    const float* bo = (const float*)d_in[6];
    const float* Wz = (const float*)d_in[7];
    const float* bz = (const float*)d_in[8];
    const float* Tf = (const float*)d_in[9];
    const float* To = (const float*)d_in[10];
    const float* Tz = (const float*)d_in[11];
    float* out = (float*)d_out;
    char*  ws  = (char*)d_ws;

    // allow >64KB dynamic LDS for the scan (harmless no-op if already set)
    hipFuncSetAttribute((const void*)scan_kernel,
                        hipFuncAttributeMaxDynamicSharedMemorySize, (int)L_TOTAL);

    t_transpose<<<dim3(768), dim3(256), 0, stream>>>(Tf, To, Tz, ws);
    k0_root<<<dim3(64), dim3(256), 0, stream>>>(te, Wf, bf, Wo, bo, Wz, bz, out, ws);
    v_gemm<<<dim3(3072), dim3(256), 0, stream>>>(ws);
    bar_init<<<dim3(1), dim3(64), 0, stream>>>(ws);

    void* args[] = { (void*)&conn, (void*)&out, (void*)&ws };
    hipLaunchCooperativeKernel((const void*)scan_kernel, dim3(64), dim3(256),
                               (void**)args, (unsigned)L_TOTAL, stream);
}

// Round 3
// 2964.744 us; speedup vs baseline: 3.8136x; 1.4556x over previous
//
#include <hip/hip_runtime.h>
#include <hip/hip_bf16.h>

typedef __bf16 bf16x8 __attribute__((ext_vector_type(8)));
typedef float floatx4 __attribute__((ext_vector_type(4)));
typedef int   intx4  __attribute__((ext_vector_type(4)));
typedef unsigned long long ull;

#define B_ 16
#define N_ 512
#define I_ 512
#define H_ 1024

// workspace byte offsets
constexpr size_t OFF_TT  = 0;                               // Tt bf16 (dead after v_gemm; then barrier+worklist live here)
constexpr size_t OFF_V   = OFF_TT + 3ull * H_ * H_ * 2;     // V bf16
constexpr size_t OFF_F0  = OFF_V + 3ull * H_ * H_ * 2;      // f0,o0,z0 fp32
constexpr size_t OFF_C   = OFF_F0 + 3ull * B_ * H_ * 4;     // tree_c fp32 (WG-column-private)
constexpr size_t OFF_HBF = OFF_C + (size_t)B_ * N_ * H_ * 4;// h bf16 shadow (cross-WG -> sc1 only)

// worklist region (inside dead Tt region, used only after v_gemm)
constexpr size_t OFF_BAR   = OFF_TT;                        // barrier counter (1 uint)
constexpr size_t OFF_PAIRS = OFF_TT + 1024;                 // 8176 packed pairs (int)
constexpr size_t OFF_LOFF  = OFF_PAIRS + 32768;             // offs[0..512] + maxlvl at [513]

// scan dynamic LDS layout
constexpr size_t L_SWZ  = 0;                                // swizzled V: 3*32*64*16B = 98304
constexpr size_t L_PAIR = 98304;                            // 8176*4 -> pad 32768
constexpr size_t L_OFF  = 131072;                           // 514*4 -> pad 2080
constexpr size_t L_C    = 133152;                           // 3*16*17*4 = 3264
constexpr size_t L_TOTAL= 136416;

#define NPAIRS (B_ * (N_ - 1))   // 8176

// ---------------------------------------------------------------------------
// Kernel 1: Tt[g][j][k] = bf16(T_g[k][j])
// ---------------------------------------------------------------------------
__global__ void __launch_bounds__(256)
t_transpose(const float* __restrict__ Tf, const float* __restrict__ To,
            const float* __restrict__ Tz, char* __restrict__ ws)
{
    __shared__ float tile[64][65];
    int g   = blockIdx.x >> 8;
    int rem = blockIdx.x & 255;
    int tj = rem >> 4, tk = rem & 15;
    const float* T = (g == 0) ? Tf : (g == 1) ? To : Tz;
    int c  = threadIdx.x & 63;
    int r0 = threadIdx.x >> 6;
#pragma unroll
    for (int l = 0; l < 16; ++l) {
        int r = l * 4 + r0;
        tile[r][c] = T[(size_t)(tk * 64 + r) * H_ + tj * 64 + c];
    }
    __syncthreads();
    __hip_bfloat16* Tt = (__hip_bfloat16*)(ws + OFF_TT) + (size_t)g * H_ * H_;
#pragma unroll
    for (int l = 0; l < 16; ++l) {
        int rr = l * 4 + r0;
        Tt[(size_t)(tj * 64 + rr) * H_ + tk * 64 + c] = __float2bfloat16(tile[c][rr]);
    }
}

// ---------------------------------------------------------------------------
// Kernel 2: root node -- f0/o0/z0 = x0 @ W + b ; root h,c ; bf16 h shadow
// ---------------------------------------------------------------------------
__global__ void __launch_bounds__(256)
k0_root(const float* __restrict__ te,
        const float* __restrict__ Wf, const float* __restrict__ bfv,
        const float* __restrict__ Wo, const float* __restrict__ bov,
        const float* __restrict__ Wz, const float* __restrict__ bzv,
        float* __restrict__ out, char* __restrict__ ws)
{
    __shared__ float x0[I_];
    int b = blockIdx.x >> 2;
    int h = ((blockIdx.x & 3) << 8) + threadIdx.x;
    for (int k = threadIdx.x; k < I_; k += 256)
        x0[k] = te[(size_t)b * N_ * I_ + k];
    __syncthreads();
    float af = bfv[h], ao = bov[h], az = bzv[h];
#pragma unroll 4
    for (int k = 0; k < I_; ++k) {
        float x = x0[k];
        af = fmaf(x, Wf[k * H_ + h], af);
        ao = fmaf(x, Wo[k * H_ + h], ao);
        az = fmaf(x, Wz[k * H_ + h], az);
    }
    float* f0 = (float*)(ws + OFF_F0);
    f0[b * H_ + h]               = af;
    f0[B_ * H_ + b * H_ + h]     = ao;
    f0[2 * B_ * H_ + b * H_ + h] = az;
    float f = 1.0f / (1.0f + __expf(-af));
    float o = 1.0f / (1.0f + __expf(-ao));
    float z = tanhf(az);
    float c = z * (1.0f - f);
    float hh = o * tanhf(c);
    size_t idx = (size_t)b * N_ * H_ + h;   // node 0
    ((float*)(ws + OFF_C))[idx] = c;
    out[idx] = hh;
    ((__hip_bfloat16*)(ws + OFF_HBF))[idx] = __float2bfloat16(hh);
}

// ---------------------------------------------------------------------------
// Kernel 3: V_g = Tt_g · Tt_g^T  (== T^T T), bf16 MFMA
// ---------------------------------------------------------------------------
__global__ void __launch_bounds__(256)
v_gemm(char* __restrict__ ws)
{
    int wv  = (blockIdx.x << 2) + (threadIdx.x >> 6);
    int g   = wv >> 12;
    int rem = wv & 4095;
    int mt = rem >> 6, ntt = rem & 63;
    int lane = threadIdx.x & 63;
    int q = lane >> 4, m = lane & 15;
    const __bf16* Tt = (const __bf16*)(ws + OFF_TT) + (size_t)g * H_ * H_;
    const __bf16* pA = Tt + (size_t)(mt * 16 + m) * H_ + q * 8;
    const __bf16* pB = Tt + (size_t)(ntt * 16 + m) * H_ + q * 8;
    floatx4 acc0 = {0.f, 0.f, 0.f, 0.f}, acc1 = {0.f, 0.f, 0.f, 0.f};
#pragma unroll 4
    for (int c = 0; c < 32; c += 2) {
        bf16x8 a0 = *(const bf16x8*)(pA + c * 32);
        bf16x8 b0 = *(const bf16x8*)(pB + c * 32);
        bf16x8 a1 = *(const bf16x8*)(pA + c * 32 + 32);
        bf16x8 b1 = *(const bf16x8*)(pB + c * 32 + 32);
        acc0 = __builtin_amdgcn_mfma_f32_16x16x32_bf16(a0, b0, acc0, 0, 0, 0);
        acc1 = __builtin_amdgcn_mfma_f32_16x16x32_bf16(a1, b1, acc1, 0, 0, 0);
    }
    floatx4 acc = acc0 + acc1;
    __hip_bfloat16* V = (__hip_bfloat16*)(ws + OFF_V) + (size_t)g * H_ * H_;
#pragma unroll
    for (int r = 0; r < 4; ++r)
        V[(size_t)(mt * 16 + q * 4 + r) * H_ + ntt * 16 + m] = __float2bfloat16(acc[r]);
}

// ---------------------------------------------------------------------------
// Kernel 3b: prep -- per-batch node levels, counting-sort (b,i,p) pairs by
// level into a global worklist. Single WG. Also zeroes the barrier counter.
// Runs AFTER v_gemm (reuses the dead Tt region for output).
// ---------------------------------------------------------------------------
__global__ void __launch_bounds__(256)
prep(const int* __restrict__ conn, char* __restrict__ ws)
{
    __shared__ int            conn_s[B_ * N_];      // 32 KB, [b][i]
    __shared__ unsigned short lvl[B_ * N_];         // 16 KB
    __shared__ int            hist[N_];
    __shared__ int            offs[N_ + 1];
    __shared__ int            cursor[N_];
    __shared__ int            mlv;

    int t = threadIdx.x;
    for (int idx = t; idx < B_ * N_; idx += 256) conn_s[idx] = conn[idx];
    for (int l = t; l < N_; l += 256) hist[l] = 0;
    __syncthreads();
    if (t < B_) {
        int b = t;
        lvl[b * N_] = 0;
        for (int i = 1; i < N_; ++i)
            lvl[b * N_ + i] = lvl[b * N_ + conn_s[b * N_ + i]] + 1;
    }
    __syncthreads();
    for (int idx = t; idx < B_ * N_; idx += 256) {
        if (idx & (N_ - 1)) atomicAdd(&hist[lvl[idx]], 1);
    }
    __syncthreads();
    if (t == 0) {
        int s = 0, ml = 0;
        for (int l = 0; l < N_; ++l) {
            offs[l] = s; s += hist[l];
            if (hist[l] > 0) ml = l;
        }
        offs[N_] = s;
        mlv = ml;
        *(unsigned*)(ws + OFF_BAR) = 0u;
    }
    __syncthreads();
    for (int l = t; l < N_; l += 256) cursor[l] = offs[l];
    __syncthreads();
    int* gpairs = (int*)(ws + OFF_PAIRS);
    for (int idx = t; idx < B_ * N_; idx += 256) {
        int i = idx & (N_ - 1);
        if (i) {
            int b = idx >> 9;
            int L = lvl[idx];
            int pos = atomicAdd(&cursor[L], 1);
            gpairs[pos] = (b << 18) | (i << 9) | conn_s[idx];
        }
    }
    int* goffs = (int*)(ws + OFF_LOFF);
    for (int l = t; l <= N_; l += 256) goffs[l] = offs[l];
    if (t == 0) goffs[N_ + 1] = mlv;
}

// ---------------------------------------------------------------------------
// Kernel 4: level-scheduled scan. 64 WGs (16 H-cols each). Per round r:
// process all (b,i) pairs at level r as 16-row MFMA tiles (arbitrary pairs as
// M-rows: A = gather of parent h rows via batched sc1 asm loads; B = V slice
// pre-swizzled in LDS, conflict-free ds_read_b128). One MALL barrier / round.
// ---------------------------------------------------------------------------
#define LDA(i, o) asm volatile("global_load_dwordx4 %0, %1, off offset:" #o " sc1" \
                               : "=v"(a[i].i4) : "v"(pa))

__global__ void __launch_bounds__(256, 1)
scan_kernel(float* __restrict__ out, char* __restrict__ ws)
{
    extern __shared__ char lds[];
    __bf16* swizzV = (__bf16*)(lds + L_SWZ);
    int*    pairsL = (int*)(lds + L_PAIR);
    int*    offsL  = (int*)(lds + L_OFF);
    float*  ldsC   = (float*)(lds + L_C);

    const int t    = threadIdx.x;
    const int wave = t >> 6;
    const int lane = t & 63;
    const int q = lane >> 4;
    const int m = lane & 15;
    const int nt = blockIdx.x;            // 64 tiles of 16 H-columns

    // stage V swizzled: chunk j=(g,c,lane) -> V_g[row=nt*16+m][k=c*32+q*8 ..+7]
    const __bf16* Vg = (const __bf16*)(ws + OFF_V);
    for (int j = t; j < 6144; j += 256) {
        int g  = j >> 11;
        int c  = (j >> 6) & 31;
        int ln = j & 63;
        int qq = ln >> 4, mm = ln & 15;
        bf16x8 v = *(const bf16x8*)(Vg + (size_t)g * H_ * H_
                                       + (size_t)(nt * 16 + mm) * H_ + c * 32 + qq * 8);
        *(bf16x8*)(swizzV + (size_t)j * 8) = v;
    }
    for (int idx = t; idx < NPAIRS; idx += 256)
        pairsL[idx] = ((const int*)(ws + OFF_PAIRS))[idx];
    for (int l = t; l < 514; l += 256)
        offsL[l] = ((const int*)(ws + OFF_LOFF))[l];
    __syncthreads();

    const int maxlvl = offsL[N_ + 1];
    const char* hbbase = (const char*)(ws + OFF_HBF);
    ull*        hbw    = (ull*)(ws + OFF_HBF);
    const float* __restrict__ f0 = (const float*)(ws + OFF_F0);
    const float* __restrict__ o0 = f0 + B_ * H_;
    const float* __restrict__ z0 = o0 + B_ * H_;
    float* __restrict__ tc = (float*)(ws + OFF_C);
    unsigned* bar = (unsigned*)(ws + OFF_BAR);

    const __bf16* vb0 = swizzV + ((size_t)(wave < 3 ? wave : 0) * 2048 + lane) * 8;

    union AFrag { intx4 i4; bf16x8 v; };

    for (int r = 1; r <= maxlvl; ++r) {
        const int s = offsL[r], e = offsL[r + 1];
        for (int ts = s; ts < e; ts += 16) {
            if (wave < 3) {
                int idx = ts + m; if (idx > e - 1) idx = e - 1;
                int pk  = pairsL[idx];
                int b   = pk >> 18;
                int p   = pk & 511;
                const void* pa = hbbase + (((size_t)(b * N_ + p)) * H_ + q * 8) * 2;
                AFrag a[32];
                LDA(0,0);     LDA(1,64);    LDA(2,128);   LDA(3,192);
                LDA(4,256);   LDA(5,320);   LDA(6,384);   LDA(7,448);
                LDA(8,512);   LDA(9,576);   LDA(10,640);  LDA(11,704);
                LDA(12,768);  LDA(13,832);  LDA(14,896);  LDA(15,960);
                LDA(16,1024); LDA(17,1088); LDA(18,1152); LDA(19,1216);
                LDA(20,1280); LDA(21,1344); LDA(22,1408); LDA(23,1472);
                LDA(24,1536); LDA(25,1600); LDA(26,1664); LDA(27,1728);
                LDA(28,1792); LDA(29,1856); LDA(30,1920); LDA(31,1984);
                asm volatile("s_waitcnt vmcnt(0)" ::: "memory");
                floatx4 a0 = {0.f,0.f,0.f,0.f}, a1 = {0.f,0.f,0.f,0.f};
                floatx4 a2 = {0.f,0.f,0.f,0.f}, a3 = {0.f,0.f,0.f,0.f};
#pragma unroll
                for (int c = 0; c < 32; ++c) {
                    bf16x8 bv = *(const bf16x8*)(vb0 + (size_t)c * 512);
                    switch (c & 3) {
                    case 0:  a0 = __builtin_amdgcn_mfma_f32_16x16x32_bf16(a[c].v, bv, a0, 0, 0, 0); break;
                    case 1:  a1 = __builtin_amdgcn_mfma_f32_16x16x32_bf16(a[c].v, bv, a1, 0, 0, 0); break;
                    case 2:  a2 = __builtin_amdgcn_mfma_f32_16x16x32_bf16(a[c].v, bv, a2, 0, 0, 0); break;
                    default: a3 = __builtin_amdgcn_mfma_f32_16x16x32_bf16(a[c].v, bv, a3, 0, 0, 0); break;
                    }
                }
                floatx4 acc = (a0 + a1) + (a2 + a3);
#pragma unroll
                for (int rr = 0; rr < 4; ++rr)
                    ldsC[(wave * 16 + q * 4 + rr) * 17 + m] = acc[rr];  // row=pair, col=n
            }
            __syncthreads();
            if (t < 64) {
                int pr = t >> 2, n0 = (t & 3) << 2;
                int idx = ts + pr; if (idx > e - 1) idx = e - 1;
                int pk = pairsL[idx];
                int b = pk >> 18, i = (pk >> 9) & 511, p = pk & 511;
                int hcol0 = nt * 16 + n0;
                floatx4 fv = *(const floatx4*)&f0[b * H_ + hcol0];
                floatx4 ov = *(const floatx4*)&o0[b * H_ + hcol0];
                floatx4 zv = *(const floatx4*)&z0[b * H_ + hcol0];
                floatx4 pc = *(const floatx4*)&tc[((size_t)(b * N_ + p)) * H_ + hcol0];
                floatx4 cc, hv;
                union { ull u; __hip_bfloat16 h4[4]; } up;
#pragma unroll
                for (int j = 0; j < 4; ++j) {
                    float af = ldsC[(0 * 16 + pr) * 17 + n0 + j] + fv[j];
                    float ao = ldsC[(1 * 16 + pr) * 17 + n0 + j] + ov[j];
                    float az = ldsC[(2 * 16 + pr) * 17 + n0 + j] + zv[j];
                    float f = 1.0f / (1.0f + __expf(-af));
                    float o = 1.0f / (1.0f + __expf(-ao));
                    float z = tanhf(az);
                    float c = pc[j] * f + z * (1.0f - f);
                    float h = o * tanhf(c);
                    cc[j] = c; hv[j] = h;
                    up.h4[j] = __float2bfloat16(h);
                }
                size_t idxI = ((size_t)(b * N_ + i)) * H_ + hcol0;
                *(floatx4*)&tc[idxI]  = cc;
                *(floatx4*)&out[idxI] = hv;
                __hip_atomic_store(hbw + (idxI >> 2), up.u,
                                   __ATOMIC_RELAXED, __HIP_MEMORY_SCOPE_AGENT);
            }
            __syncthreads();
        }
        if (r < maxlvl) {
            if (t == 0) {
                __hip_atomic_fetch_add(bar, 1u, __ATOMIC_RELAXED, __HIP_MEMORY_SCOPE_AGENT);
                unsigned tgt = 64u * (unsigned)r;
                while (__hip_atomic_load(bar, __ATOMIC_RELAXED, __HIP_MEMORY_SCOPE_AGENT) < tgt) {}
            }
            __syncthreads();
        }
    }
}

// ---------------------------------------------------------------------------
extern "C" void kernel_launch(void* const* d_in, const int* in_sizes, int n_in,
                              void* d_out, int out_size, void* d_ws, size_t ws_size,
                              hipStream_t stream)
{
    const float* te  = (const float*)d_in[0];
    const int*  conn = (const int*)d_in[1];
    const float* Wf = (const float*)d_in[3];
    const float* bf = (const float*)d_in[4];
    const float* Wo = (const float*)d_in[5];
    const float* bo = (const float*)d_in[6];
    const float* Wz = (const float*)d_in[7];
    const float* bz = (const float*)d_in[8];
    const float* Tf = (const float*)d_in[9];
    const float* To = (const float*)d_in[10];
    const float* Tz = (const float*)d_in[11];
    float* out = (float*)d_out;
    char*  ws  = (char*)d_ws;

    hipFuncSetAttribute((const void*)scan_kernel,
                        hipFuncAttributeMaxDynamicSharedMemorySize, (int)L_TOTAL);

    t_transpose<<<dim3(768), dim3(256), 0, stream>>>(Tf, To, Tz, ws);
    k0_root<<<dim3(64), dim3(256), 0, stream>>>(te, Wf, bf, Wo, bo, Wz, bz, out, ws);
    v_gemm<<<dim3(3072), dim3(256), 0, stream>>>(ws);
    prep<<<dim3(1), dim3(256), 0, stream>>>(conn, ws);

    void* args[] = { (void*)&out, (void*)&ws };
    hipLaunchCooperativeKernel((const void*)scan_kernel, dim3(64), dim3(256),
                               (void**)args, (unsigned)L_TOTAL, stream);
}

// Round 5
// 1691.810 us; speedup vs baseline: 6.6830x; 1.7524x over previous
//
#include <hip/hip_runtime.h>
#include <hip/hip_bf16.h>

typedef __bf16 bf16x8 __attribute__((ext_vector_type(8)));
typedef float floatx4 __attribute__((ext_vector_type(4)));
typedef unsigned long long ull;

#define B_ 16
#define N_ 512
#define I_ 512
#define H_ 1024

// workspace byte offsets
constexpr size_t OFF_TT  = 0;                               // Tt bf16 (dead after v_gemm)
constexpr size_t OFF_V   = OFF_TT + 3ull * H_ * H_ * 2;     // V bf16
constexpr size_t OFF_F0  = OFF_V + 3ull * H_ * H_ * 2;      // f0,o0,z0 fp32
constexpr size_t OFF_C   = OFF_F0 + 3ull * B_ * H_ * 4;     // tree_c fp32 (cross-WG -> atomic agent)
constexpr size_t OFF_HBF = OFF_C + (size_t)B_ * N_ * H_ * 4;// h bf16 shadow (cross-WG -> atomic agent)

// worklist region (inside dead Tt region; written by prep after v_gemm)
constexpr size_t OFF_BAR   = OFF_TT;                        // barrier counter
constexpr size_t OFF_PAIRS = OFF_TT + 1024;                 // 8176 packed pairs
constexpr size_t OFF_LOFF  = OFF_PAIRS + 32768;             // offs[0..512], maxlvl at [513]

#define NPAIRS (B_ * (N_ - 1))

#define AT_LD(p)     __hip_atomic_load((p), __ATOMIC_RELAXED, __HIP_MEMORY_SCOPE_AGENT)
#define AT_ST(p, v)  __hip_atomic_store((p), (v), __ATOMIC_RELAXED, __HIP_MEMORY_SCOPE_AGENT)

// ---------------------------------------------------------------------------
// Kernel 1: Tt[g][j][k] = bf16(T_g[k][j])
// ---------------------------------------------------------------------------
__global__ void __launch_bounds__(256)
t_transpose(const float* __restrict__ Tf, const float* __restrict__ To,
            const float* __restrict__ Tz, char* __restrict__ ws)
{
    __shared__ float tile[64][65];
    int g   = blockIdx.x >> 8;
    int rem = blockIdx.x & 255;
    int tj = rem >> 4, tk = rem & 15;
    const float* T = (g == 0) ? Tf : (g == 1) ? To : Tz;
    int c  = threadIdx.x & 63;
    int r0 = threadIdx.x >> 6;
#pragma unroll
    for (int l = 0; l < 16; ++l) {
        int r = l * 4 + r0;
        tile[r][c] = T[(size_t)(tk * 64 + r) * H_ + tj * 64 + c];
    }
    __syncthreads();
    __hip_bfloat16* Tt = (__hip_bfloat16*)(ws + OFF_TT) + (size_t)g * H_ * H_;
#pragma unroll
    for (int l = 0; l < 16; ++l) {
        int rr = l * 4 + r0;
        Tt[(size_t)(tj * 64 + rr) * H_ + tk * 64 + c] = __float2bfloat16(tile[c][rr]);
    }
}

// ---------------------------------------------------------------------------
// Kernel 2: root node -- f0/o0/z0 = x0 @ W + b ; root h,c ; bf16 h shadow
// ---------------------------------------------------------------------------
__global__ void __launch_bounds__(256)
k0_root(const float* __restrict__ te,
        const float* __restrict__ Wf, const float* __restrict__ bfv,
        const float* __restrict__ Wo, const float* __restrict__ bov,
        const float* __restrict__ Wz, const float* __restrict__ bzv,
        float* __restrict__ out, char* __restrict__ ws)
{
    __shared__ float x0[I_];
    int b = blockIdx.x >> 2;
    int h = ((blockIdx.x & 3) << 8) + threadIdx.x;
    for (int k = threadIdx.x; k < I_; k += 256)
        x0[k] = te[(size_t)b * N_ * I_ + k];
    __syncthreads();
    float af = bfv[h], ao = bov[h], az = bzv[h];
#pragma unroll 4
    for (int k = 0; k < I_; ++k) {
        float x = x0[k];
        af = fmaf(x, Wf[k * H_ + h], af);
        ao = fmaf(x, Wo[k * H_ + h], ao);
        az = fmaf(x, Wz[k * H_ + h], az);
    }
    float* f0 = (float*)(ws + OFF_F0);
    f0[b * H_ + h]               = af;
    f0[B_ * H_ + b * H_ + h]     = ao;
    f0[2 * B_ * H_ + b * H_ + h] = az;
    float f = 1.0f / (1.0f + __expf(-af));
    float o = 1.0f / (1.0f + __expf(-ao));
    float z = tanhf(az);
    float c = z * (1.0f - f);
    float hh = o * tanhf(c);
    size_t idx = (size_t)b * N_ * H_ + h;
    ((float*)(ws + OFF_C))[idx] = c;
    out[idx] = hh;
    ((__hip_bfloat16*)(ws + OFF_HBF))[idx] = __float2bfloat16(hh);
}

// ---------------------------------------------------------------------------
// Kernel 3: V_g = Tt_g · Tt_g^T, 64x64 output per wave
// ---------------------------------------------------------------------------
__global__ void __launch_bounds__(64)
v_gemm(char* __restrict__ ws)
{
    int blk = blockIdx.x;
    int g   = blk >> 8;
    int rem = blk & 255;
    int mg = rem >> 4, ng = rem & 15;
    int lane = threadIdx.x;
    int q = lane >> 4, m = lane & 15;
    const __bf16* Tt = (const __bf16*)(ws + OFF_TT) + (size_t)g * H_ * H_;
    const __bf16* pa = Tt + (size_t)(mg * 64 + m) * H_ + q * 8;
    const __bf16* pb = Tt + (size_t)(ng * 64 + m) * H_ + q * 8;

    floatx4 acc[4][4];
#pragma unroll
    for (int ti = 0; ti < 4; ++ti)
#pragma unroll
        for (int tj = 0; tj < 4; ++tj)
            acc[ti][tj] = (floatx4){0.f, 0.f, 0.f, 0.f};

#pragma unroll 2
    for (int c = 0; c < 32; ++c) {
        bf16x8 a0 = *(const bf16x8*)(pa + c * 32);
        bf16x8 a1 = *(const bf16x8*)(pa + 16 * H_ + c * 32);
        bf16x8 a2 = *(const bf16x8*)(pa + 32 * H_ + c * 32);
        bf16x8 a3 = *(const bf16x8*)(pa + 48 * H_ + c * 32);
        bf16x8 b0 = *(const bf16x8*)(pb + c * 32);
        bf16x8 b1 = *(const bf16x8*)(pb + 16 * H_ + c * 32);
        bf16x8 b2 = *(const bf16x8*)(pb + 32 * H_ + c * 32);
        bf16x8 b3 = *(const bf16x8*)(pb + 48 * H_ + c * 32);
        acc[0][0] = __builtin_amdgcn_mfma_f32_16x16x32_bf16(a0, b0, acc[0][0], 0, 0, 0);
        acc[0][1] = __builtin_amdgcn_mfma_f32_16x16x32_bf16(a0, b1, acc[0][1], 0, 0, 0);
        acc[0][2] = __builtin_amdgcn_mfma_f32_16x16x32_bf16(a0, b2, acc[0][2], 0, 0, 0);
        acc[0][3] = __builtin_amdgcn_mfma_f32_16x16x32_bf16(a0, b3, acc[0][3], 0, 0, 0);
        acc[1][0] = __builtin_amdgcn_mfma_f32_16x16x32_bf16(a1, b0, acc[1][0], 0, 0, 0);
        acc[1][1] = __builtin_amdgcn_mfma_f32_16x16x32_bf16(a1, b1, acc[1][1], 0, 0, 0);
        acc[1][2] = __builtin_amdgcn_mfma_f32_16x16x32_bf16(a1, b2, acc[1][2], 0, 0, 0);
        acc[1][3] = __builtin_amdgcn_mfma_f32_16x16x32_bf16(a1, b3, acc[1][3], 0, 0, 0);
        acc[2][0] = __builtin_amdgcn_mfma_f32_16x16x32_bf16(a2, b0, acc[2][0], 0, 0, 0);
        acc[2][1] = __builtin_amdgcn_mfma_f32_16x16x32_bf16(a2, b1, acc[2][1], 0, 0, 0);
        acc[2][2] = __builtin_amdgcn_mfma_f32_16x16x32_bf16(a2, b2, acc[2][2], 0, 0, 0);
        acc[2][3] = __builtin_amdgcn_mfma_f32_16x16x32_bf16(a2, b3, acc[2][3], 0, 0, 0);
        acc[3][0] = __builtin_amdgcn_mfma_f32_16x16x32_bf16(a3, b0, acc[3][0], 0, 0, 0);
        acc[3][1] = __builtin_amdgcn_mfma_f32_16x16x32_bf16(a3, b1, acc[3][1], 0, 0, 0);
        acc[3][2] = __builtin_amdgcn_mfma_f32_16x16x32_bf16(a3, b2, acc[3][2], 0, 0, 0);
        acc[3][3] = __builtin_amdgcn_mfma_f32_16x16x32_bf16(a3, b3, acc[3][3], 0, 0, 0);
    }
    __hip_bfloat16* V = (__hip_bfloat16*)(ws + OFF_V) + (size_t)g * H_ * H_;
#pragma unroll
    for (int ti = 0; ti < 4; ++ti)
#pragma unroll
        for (int tj = 0; tj < 4; ++tj)
#pragma unroll
            for (int rr = 0; rr < 4; ++rr)
                V[(size_t)(mg * 64 + ti * 16 + q * 4 + rr) * H_ + ng * 64 + tj * 16 + m]
                    = __float2bfloat16(acc[ti][tj][rr]);
}

// ---------------------------------------------------------------------------
// Kernel 4: prep (round-3-proven version) -- levels, counting-sort worklist,
// zero barrier. Single WG.
// ---------------------------------------------------------------------------
__global__ void __launch_bounds__(256)
prep(const int* __restrict__ conn, char* __restrict__ ws)
{
    __shared__ int            conn_s[B_ * N_];
    __shared__ unsigned short lvl[B_ * N_];
    __shared__ int            hist[N_];
    __shared__ int            offs[N_ + 1];
    __shared__ int            cursor[N_];
    __shared__ int            mlv;

    int t = threadIdx.x;
    for (int idx = t; idx < B_ * N_; idx += 256) conn_s[idx] = conn[idx];
    for (int l = t; l < N_; l += 256) hist[l] = 0;
    __syncthreads();
    if (t < B_) {
        int b = t;
        lvl[b * N_] = 0;
        for (int i = 1; i < N_; ++i)
            lvl[b * N_ + i] = lvl[b * N_ + conn_s[b * N_ + i]] + 1;
    }
    __syncthreads();
    for (int idx = t; idx < B_ * N_; idx += 256) {
        if (idx & (N_ - 1)) atomicAdd(&hist[lvl[idx]], 1);
    }
    __syncthreads();
    if (t == 0) {
        int s = 0, ml = 0;
        for (int l = 0; l < N_; ++l) {
            offs[l] = s; s += hist[l];
            if (hist[l] > 0) ml = l;
        }
        offs[N_] = s;
        mlv = ml;
        *(unsigned*)(ws + OFF_BAR) = 0u;
    }
    __syncthreads();
    for (int l = t; l < N_; l += 256) cursor[l] = offs[l];
    __syncthreads();
    int* gpairs = (int*)(ws + OFF_PAIRS);
    for (int idx = t; idx < B_ * N_; idx += 256) {
        int i = idx & (N_ - 1);
        if (i) {
            int b = idx >> 9;
            int L = lvl[idx];
            int pos = atomicAdd(&cursor[L], 1);
            gpairs[pos] = (b << 18) | (i << 9) | conn_s[idx];
        }
    }
    int* goffs = (int*)(ws + OFF_LOFF);
    for (int l = t; l <= N_; l += 256) goffs[l] = offs[l];
    if (t == 0) goffs[N_ + 1] = mlv;
}

// ---------------------------------------------------------------------------
// Kernel 5: level-scheduled scan. 256 WGs = 64 col-slices x 4 pair-groups.
// NO inline asm: all cross-WG traffic via compiler-tracked agent atomics.
// waves 0-2: gates (V persistent in regs, A from read-order-swizzled LDS);
// wave 3: epilogue (pc atomic prefetch, LSTM cell, agent-atomic stores).
// ---------------------------------------------------------------------------
__global__ void __launch_bounds__(256, 1)
scan_kernel(float* __restrict__ out, char* __restrict__ ws)
{
    __shared__ __bf16 aSwz[16384];          // 32 KB swizzled A tile
    __shared__ float  ldsC[3 * 16 * 17];

    const int t    = threadIdx.x;
    const int wave = t >> 6;
    const int lane = t & 63;
    const int q = lane >> 4;
    const int m = lane & 15;
    const int cs = blockIdx.x & 63;         // column slice (16 H-cols)
    const int pg = blockIdx.x >> 6;         // pair group (0..3)

    const int* __restrict__ pairsG = (const int*)(ws + OFF_PAIRS);
    const int* __restrict__ offsG  = (const int*)(ws + OFF_LOFF);
    const ull* hbu = (const ull*)(ws + OFF_HBF);
    ull*       hbw = (ull*)(ws + OFF_HBF);
    const float* __restrict__ f0 = (const float*)(ws + OFF_F0);
    const float* __restrict__ o0 = f0 + B_ * H_;
    const float* __restrict__ z0 = o0 + B_ * H_;
    ull*      tcu = (ull*)(ws + OFF_C);
    float*    out_f = out;
    unsigned* bar = (unsigned*)(ws + OFF_BAR);

    // persistent V fragments: 32 bf16x8 per gate lane (fully unrolled -> regs)
    bf16x8 vb[32];
    if (wave < 3) {
        const __bf16* vbase = (const __bf16*)(ws + OFF_V) + (size_t)wave * H_ * H_
                              + (size_t)(cs * 16 + m) * H_ + q * 8;
#pragma unroll
        for (int i = 0; i < 32; ++i) vb[i] = *(const bf16x8*)(vbase + i * 32);
    }

    const int maxlvl = offsG[N_ + 1];
    const int rid = t & 15;                 // staged pair slot
    const int ck  = t >> 4;                 // 128B chunk within row
    char* stDst = (char*)aSwz + ck * 2048 + rid * 16;
    const char* aB = (const char*)aSwz + lane * 16;

    for (int r = 1; r <= maxlvl; ++r) {
        const int lo = offsG[r], hi = offsG[r + 1];
        const int ntile = (hi - lo + 15) >> 4;
        for (int tt = pg; tt < ntile; tt += 4) {
            const int curTs = lo + (tt << 4);

            // A staging loads: 16x 8B agent-atomic per thread (one 128B chunk)
            int idx = curTs + rid; if (idx > hi - 1) idx = hi - 1;
            int pk = pairsG[idx];
            const ull* src = hbu + ((((size_t)((pk >> 18) * N_ + (pk & 511))) * H_) >> 2)
                                 + (size_t)ck * 16;
            ull u[16];
#pragma unroll
            for (int j = 0; j < 16; ++j) u[j] = AT_LD(src + j);

            // wave3: parent-c prefetch for this tile
            ull pc0 = 0, pc1 = 0;
            if (wave == 3) {
                int idx2 = curTs + (lane >> 2); if (idx2 > hi - 1) idx2 = hi - 1;
                int pk2 = pairsG[idx2];
                const ull* pca = tcu + ((((size_t)((pk2 >> 18) * N_ + (pk2 & 511))) * H_
                                         + cs * 16 + (lane & 3) * 4) >> 1);
                pc0 = AT_LD(pca);
                pc1 = AT_LD(pca + 1);
            }

            __syncthreads();                // S_a: prev tile fully consumed
#pragma unroll
            for (int j = 0; j < 8; ++j) {
                *(ull*)(stDst + j * 256)     = u[2 * j];
                *(ull*)(stDst + j * 256 + 8) = u[2 * j + 1];
            }
            __syncthreads();                // S_b: aSwz visible

            if (wave < 3) {
                floatx4 acc0 = {0.f,0.f,0.f,0.f}, acc1 = {0.f,0.f,0.f,0.f};
                floatx4 acc2 = {0.f,0.f,0.f,0.f}, acc3 = {0.f,0.f,0.f,0.f};
#pragma unroll
                for (int c = 0; c < 32; ++c) {
                    bf16x8 av = *(const bf16x8*)(aB + c * 1024);
                    switch (c & 3) {
                    case 0:  acc0 = __builtin_amdgcn_mfma_f32_16x16x32_bf16(av, vb[c], acc0, 0, 0, 0); break;
                    case 1:  acc1 = __builtin_amdgcn_mfma_f32_16x16x32_bf16(av, vb[c], acc1, 0, 0, 0); break;
                    case 2:  acc2 = __builtin_amdgcn_mfma_f32_16x16x32_bf16(av, vb[c], acc2, 0, 0, 0); break;
                    default: acc3 = __builtin_amdgcn_mfma_f32_16x16x32_bf16(av, vb[c], acc3, 0, 0, 0); break;
                    }
                }
                floatx4 acc = (acc0 + acc1) + (acc2 + acc3);
                ldsC[(wave * 16 + q * 4 + 0) * 17 + m] = acc[0];
                ldsC[(wave * 16 + q * 4 + 1) * 17 + m] = acc[1];
                ldsC[(wave * 16 + q * 4 + 2) * 17 + m] = acc[2];
                ldsC[(wave * 16 + q * 4 + 3) * 17 + m] = acc[3];
            }
            __syncthreads();                // S_c: ldsC ready

            if (wave == 3) {
                int pr = lane >> 2, n0 = (lane & 3) << 2;
                int idx2 = curTs + pr; if (idx2 > hi - 1) idx2 = hi - 1;
                int pk2 = pairsG[idx2];
                int bb = pk2 >> 18, ii = (pk2 >> 9) & 511;
                int hcol0 = cs * 16 + n0;
                floatx4 fv = *(const floatx4*)&f0[bb * H_ + hcol0];
                floatx4 ov = *(const floatx4*)&o0[bb * H_ + hcol0];
                floatx4 zv = *(const floatx4*)&z0[bb * H_ + hcol0];
                union U2 { ull u; float f[2]; };
                U2 w0, w1; w0.u = pc0; w1.u = pc1;
                float pcf[4] = { w0.f[0], w0.f[1], w1.f[0], w1.f[1] };
                floatx4 cc, hv;
                ull hpack = 0;
#pragma unroll
                for (int j = 0; j < 4; ++j) {
                    float af = ldsC[(0 * 16 + pr) * 17 + n0 + j] + fv[j];
                    float ao = ldsC[(1 * 16 + pr) * 17 + n0 + j] + ov[j];
                    float az = ldsC[(2 * 16 + pr) * 17 + n0 + j] + zv[j];
                    float f = 1.0f / (1.0f + __expf(-af));
                    float o = 1.0f / (1.0f + __expf(-ao));
                    float z = tanhf(az);
                    float c = pcf[j] * f + z * (1.0f - f);
                    float h = o * tanhf(c);
                    cc[j] = c; hv[j] = h;
                    hpack |= (ull)__builtin_bit_cast(unsigned short, __float2bfloat16(h)) << (16 * j);
                }
                size_t idxI = ((size_t)(bb * N_ + ii)) * H_ + hcol0;
                U2 c01, c23;
                c01.f[0] = cc[0]; c01.f[1] = cc[1];
                c23.f[0] = cc[2]; c23.f[1] = cc[3];
                AT_ST(tcu + (idxI >> 1),     c01.u);
                AT_ST(tcu + (idxI >> 1) + 1, c23.u);
                *(floatx4*)&out_f[idxI] = hv;
                AT_ST(hbw + (idxI >> 2), hpack);
            }
        }
        if (r < maxlvl) {
            __syncthreads();                // pre-barrier drain (vmcnt0 by compiler)
            if (t == 0) {
                __hip_atomic_fetch_add(bar, 1u, __ATOMIC_RELAXED, __HIP_MEMORY_SCOPE_AGENT);
                unsigned tgt = 256u * (unsigned)r;
                while (__hip_atomic_load(bar, __ATOMIC_RELAXED, __HIP_MEMORY_SCOPE_AGENT) < tgt) {}
            }
            __syncthreads();
        }
    }
}

// ---------------------------------------------------------------------------
extern "C" void kernel_launch(void* const* d_in, const int* in_sizes, int n_in,
                              void* d_out, int out_size, void* d_ws, size_t ws_size,
                              hipStream_t stream)
{
    const float* te  = (const float*)d_in[0];
    const int*  conn = (const int*)d_in[1];
    const float* Wf = (const float*)d_in[3];
    const float* bf = (const float*)d_in[4];
    const float* Wo = (const float*)d_in[5];
    const float* bo = (const float*)d_in[6];
    const float* Wz = (const float*)d_in[7];
    const float* bz = (const float*)d_in[8];
    const float* Tf = (const float*)d_in[9];
    const float* To = (const float*)d_in[10];
    const float* Tz = (const float*)d_in[11];
    float* out = (float*)d_out;
    char*  ws  = (char*)d_ws;

    t_transpose<<<dim3(768), dim3(256), 0, stream>>>(Tf, To, Tz, ws);
    k0_root<<<dim3(64), dim3(256), 0, stream>>>(te, Wf, bf, Wo, bo, Wz, bz, out, ws);
    v_gemm<<<dim3(768), dim3(64), 0, stream>>>(ws);
    prep<<<dim3(1), dim3(256), 0, stream>>>(conn, ws);

    void* args[] = { (void*)&out, (void*)&ws };
    hipLaunchCooperativeKernel((const void*)scan_kernel, dim3(256), dim3(256),
                               (void**)args, 0, stream);
}

// Round 6
// 1675.239 us; speedup vs baseline: 6.7491x; 1.0099x over previous
//
#include <hip/hip_runtime.h>
#include <hip/hip_bf16.h>

typedef __bf16 bf16x8 __attribute__((ext_vector_type(8)));
typedef float floatx4 __attribute__((ext_vector_type(4)));
typedef unsigned long long ull;

#define B_ 16
#define N_ 512
#define I_ 512
#define H_ 1024

// workspace byte offsets
constexpr size_t OFF_TT  = 0;                               // Tt bf16 (dead after v_gemm)
constexpr size_t OFF_V   = OFF_TT + 3ull * H_ * H_ * 2;     // V bf16
constexpr size_t OFF_F0  = OFF_V + 3ull * H_ * H_ * 2;      // f0,o0,z0 fp32
constexpr size_t OFF_C   = OFF_F0 + 3ull * B_ * H_ * 4;     // tree_c fp32 (cross-WG -> atomic agent)
constexpr size_t OFF_HBF = OFF_C + (size_t)B_ * N_ * H_ * 4;// h bf16 shadow (cross-WG -> atomic agent)

// worklist region (inside dead Tt region; written by prep after v_gemm)
constexpr size_t OFF_BAR   = OFF_TT;                        // barrier counter
constexpr size_t OFF_PAIRS = OFF_TT + 1024;                 // 8176 packed pairs
constexpr size_t OFF_LOFF  = OFF_PAIRS + 32768;             // offs[0..512], maxlvl at [513]

// scan dynamic LDS layout
constexpr size_t L_A    = 0;                                // A tile: 32768
constexpr size_t L_VS   = 32768;                            // swizzled V: 3*32*64*16 = 98304
constexpr size_t L_C2   = 131072;                           // ldsC: 3*16*17*4 = 3264
constexpr size_t L_TOT  = 134336;

#define NPAIRS (B_ * (N_ - 1))

#define AT_LD(p)     __hip_atomic_load((p), __ATOMIC_RELAXED, __HIP_MEMORY_SCOPE_AGENT)
#define AT_ST(p, v)  __hip_atomic_store((p), (v), __ATOMIC_RELAXED, __HIP_MEMORY_SCOPE_AGENT)

// ---------------------------------------------------------------------------
// Kernel 1: Tt[g][j][k] = bf16(T_g[k][j])
// ---------------------------------------------------------------------------
__global__ void __launch_bounds__(256)
t_transpose(const float* __restrict__ Tf, const float* __restrict__ To,
            const float* __restrict__ Tz, char* __restrict__ ws)
{
    __shared__ float tile[64][65];
    int g   = blockIdx.x >> 8;
    int rem = blockIdx.x & 255;
    int tj = rem >> 4, tk = rem & 15;
    const float* T = (g == 0) ? Tf : (g == 1) ? To : Tz;
    int c  = threadIdx.x & 63;
    int r0 = threadIdx.x >> 6;
#pragma unroll
    for (int l = 0; l < 16; ++l) {
        int r = l * 4 + r0;
        tile[r][c] = T[(size_t)(tk * 64 + r) * H_ + tj * 64 + c];
    }
    __syncthreads();
    __hip_bfloat16* Tt = (__hip_bfloat16*)(ws + OFF_TT) + (size_t)g * H_ * H_;
#pragma unroll
    for (int l = 0; l < 16; ++l) {
        int rr = l * 4 + r0;
        Tt[(size_t)(tj * 64 + rr) * H_ + tk * 64 + c] = __float2bfloat16(tile[c][rr]);
    }
}

// ---------------------------------------------------------------------------
// Kernel 2: root node -- f0/o0/z0 = x0 @ W + b ; root h,c ; bf16 h shadow
// ---------------------------------------------------------------------------
__global__ void __launch_bounds__(256)
k0_root(const float* __restrict__ te,
        const float* __restrict__ Wf, const float* __restrict__ bfv,
        const float* __restrict__ Wo, const float* __restrict__ bov,
        const float* __restrict__ Wz, const float* __restrict__ bzv,
        float* __restrict__ out, char* __restrict__ ws)
{
    __shared__ float x0[I_];
    int b = blockIdx.x >> 2;
    int h = ((blockIdx.x & 3) << 8) + threadIdx.x;
    for (int k = threadIdx.x; k < I_; k += 256)
        x0[k] = te[(size_t)b * N_ * I_ + k];
    __syncthreads();
    float af = bfv[h], ao = bov[h], az = bzv[h];
#pragma unroll 4
    for (int k = 0; k < I_; ++k) {
        float x = x0[k];
        af = fmaf(x, Wf[k * H_ + h], af);
        ao = fmaf(x, Wo[k * H_ + h], ao);
        az = fmaf(x, Wz[k * H_ + h], az);
    }
    float* f0 = (float*)(ws + OFF_F0);
    f0[b * H_ + h]               = af;
    f0[B_ * H_ + b * H_ + h]     = ao;
    f0[2 * B_ * H_ + b * H_ + h] = az;
    float f = 1.0f / (1.0f + __expf(-af));
    float o = 1.0f / (1.0f + __expf(-ao));
    float z = tanhf(az);
    float c = z * (1.0f - f);
    float hh = o * tanhf(c);
    size_t idx = (size_t)b * N_ * H_ + h;
    ((float*)(ws + OFF_C))[idx] = c;
    out[idx] = hh;
    ((__hip_bfloat16*)(ws + OFF_HBF))[idx] = __float2bfloat16(hh);
}

// ---------------------------------------------------------------------------
// Kernel 3: V_g = Tt_g · Tt_g^T, 64x64 output per wave
// ---------------------------------------------------------------------------
__global__ void __launch_bounds__(64)
v_gemm(char* __restrict__ ws)
{
    int blk = blockIdx.x;
    int g   = blk >> 8;
    int rem = blk & 255;
    int mg = rem >> 4, ng = rem & 15;
    int lane = threadIdx.x;
    int q = lane >> 4, m = lane & 15;
    const __bf16* Tt = (const __bf16*)(ws + OFF_TT) + (size_t)g * H_ * H_;
    const __bf16* pa = Tt + (size_t)(mg * 64 + m) * H_ + q * 8;
    const __bf16* pb = Tt + (size_t)(ng * 64 + m) * H_ + q * 8;

    floatx4 acc[4][4];
#pragma unroll
    for (int ti = 0; ti < 4; ++ti)
#pragma unroll
        for (int tj = 0; tj < 4; ++tj)
            acc[ti][tj] = (floatx4){0.f, 0.f, 0.f, 0.f};

#pragma unroll 2
    for (int c = 0; c < 32; ++c) {
        bf16x8 a0 = *(const bf16x8*)(pa + c * 32);
        bf16x8 a1 = *(const bf16x8*)(pa + 16 * H_ + c * 32);
        bf16x8 a2 = *(const bf16x8*)(pa + 32 * H_ + c * 32);
        bf16x8 a3 = *(const bf16x8*)(pa + 48 * H_ + c * 32);
        bf16x8 b0 = *(const bf16x8*)(pb + c * 32);
        bf16x8 b1 = *(const bf16x8*)(pb + 16 * H_ + c * 32);
        bf16x8 b2 = *(const bf16x8*)(pb + 32 * H_ + c * 32);
        bf16x8 b3 = *(const bf16x8*)(pb + 48 * H_ + c * 32);
        acc[0][0] = __builtin_amdgcn_mfma_f32_16x16x32_bf16(a0, b0, acc[0][0], 0, 0, 0);
        acc[0][1] = __builtin_amdgcn_mfma_f32_16x16x32_bf16(a0, b1, acc[0][1], 0, 0, 0);
        acc[0][2] = __builtin_amdgcn_mfma_f32_16x16x32_bf16(a0, b2, acc[0][2], 0, 0, 0);
        acc[0][3] = __builtin_amdgcn_mfma_f32_16x16x32_bf16(a0, b3, acc[0][3], 0, 0, 0);
        acc[1][0] = __builtin_amdgcn_mfma_f32_16x16x32_bf16(a1, b0, acc[1][0], 0, 0, 0);
        acc[1][1] = __builtin_amdgcn_mfma_f32_16x16x32_bf16(a1, b1, acc[1][1], 0, 0, 0);
        acc[1][2] = __builtin_amdgcn_mfma_f32_16x16x32_bf16(a1, b2, acc[1][2], 0, 0, 0);
        acc[1][3] = __builtin_amdgcn_mfma_f32_16x16x32_bf16(a1, b3, acc[1][3], 0, 0, 0);
        acc[2][0] = __builtin_amdgcn_mfma_f32_16x16x32_bf16(a2, b0, acc[2][0], 0, 0, 0);
        acc[2][1] = __builtin_amdgcn_mfma_f32_16x16x32_bf16(a2, b1, acc[2][1], 0, 0, 0);
        acc[2][2] = __builtin_amdgcn_mfma_f32_16x16x32_bf16(a2, b2, acc[2][2], 0, 0, 0);
        acc[2][3] = __builtin_amdgcn_mfma_f32_16x16x32_bf16(a2, b3, acc[2][3], 0, 0, 0);
        acc[3][0] = __builtin_amdgcn_mfma_f32_16x16x32_bf16(a3, b0, acc[3][0], 0, 0, 0);
        acc[3][1] = __builtin_amdgcn_mfma_f32_16x16x32_bf16(a3, b1, acc[3][1], 0, 0, 0);
        acc[3][2] = __builtin_amdgcn_mfma_f32_16x16x32_bf16(a3, b2, acc[3][2], 0, 0, 0);
        acc[3][3] = __builtin_amdgcn_mfma_f32_16x16x32_bf16(a3, b3, acc[3][3], 0, 0, 0);
    }
    __hip_bfloat16* V = (__hip_bfloat16*)(ws + OFF_V) + (size_t)g * H_ * H_;
#pragma unroll
    for (int ti = 0; ti < 4; ++ti)
#pragma unroll
        for (int tj = 0; tj < 4; ++tj)
#pragma unroll
            for (int rr = 0; rr < 4; ++rr)
                V[(size_t)(mg * 64 + ti * 16 + q * 4 + rr) * H_ + ng * 64 + tj * 16 + m]
                    = __float2bfloat16(acc[ti][tj][rr]);
}

// ---------------------------------------------------------------------------
// Kernel 4: prep -- levels, counting-sort worklist, zero barrier. Single WG.
// ---------------------------------------------------------------------------
__global__ void __launch_bounds__(256)
prep(const int* __restrict__ conn, char* __restrict__ ws)
{
    __shared__ int            conn_s[B_ * N_];
    __shared__ unsigned short lvl[B_ * N_];
    __shared__ int            hist[N_];
    __shared__ int            offs[N_ + 1];
    __shared__ int            cursor[N_];
    __shared__ int            mlv;

    int t = threadIdx.x;
    for (int idx = t; idx < B_ * N_; idx += 256) conn_s[idx] = conn[idx];
    for (int l = t; l < N_; l += 256) hist[l] = 0;
    __syncthreads();
    if (t < B_) {
        int b = t;
        lvl[b * N_] = 0;
        for (int i = 1; i < N_; ++i)
            lvl[b * N_ + i] = lvl[b * N_ + conn_s[b * N_ + i]] + 1;
    }
    __syncthreads();
    for (int idx = t; idx < B_ * N_; idx += 256) {
        if (idx & (N_ - 1)) atomicAdd(&hist[lvl[idx]], 1);
    }
    __syncthreads();
    if (t == 0) {
        int s = 0, ml = 0;
        for (int l = 0; l < N_; ++l) {
            offs[l] = s; s += hist[l];
            if (hist[l] > 0) ml = l;
        }
        offs[N_] = s;
        mlv = ml;
        *(unsigned*)(ws + OFF_BAR) = 0u;
    }
    __syncthreads();
    for (int l = t; l < N_; l += 256) cursor[l] = offs[l];
    __syncthreads();
    int* gpairs = (int*)(ws + OFF_PAIRS);
    for (int idx = t; idx < B_ * N_; idx += 256) {
        int i = idx & (N_ - 1);
        if (i) {
            int b = idx >> 9;
            int L = lvl[idx];
            int pos = atomicAdd(&cursor[L], 1);
            gpairs[pos] = (b << 18) | (i << 9) | conn_s[idx];
        }
    }
    int* goffs = (int*)(ws + OFF_LOFF);
    for (int l = t; l <= N_; l += 256) goffs[l] = offs[l];
    if (t == 0) goffs[N_ + 1] = mlv;
}

// ---------------------------------------------------------------------------
// Kernel 5: level-scheduled scan. 256 WGs = 64 col-slices x 4 pair-groups.
// V slice lives in LDS, pre-swizzled in exact MFMA read order (deterministic
// ds_read_b128, conflict-free) -- no register-array remat/spill hazard.
// All cross-WG traffic via compiler-tracked agent atomics (r5-proven).
// ---------------------------------------------------------------------------
__global__ void __launch_bounds__(256, 1)
scan_kernel(float* __restrict__ out, char* __restrict__ ws)
{
    extern __shared__ char lds[];
    __bf16* aSwz   = (__bf16*)(lds + L_A);    // 32 KB swizzled A tile
    __bf16* swizzV = (__bf16*)(lds + L_VS);   // 96 KB swizzled V slice
    float*  ldsC   = (float*)(lds + L_C2);

    const int t    = threadIdx.x;
    const int wave = t >> 6;
    const int lane = t & 63;
    const int q = lane >> 4;
    const int m = lane & 15;
    const int cs = blockIdx.x & 63;         // column slice (16 H-cols)
    const int pg = blockIdx.x >> 6;         // pair group (0..3)

    const int* __restrict__ pairsG = (const int*)(ws + OFF_PAIRS);
    const int* __restrict__ offsG  = (const int*)(ws + OFF_LOFF);
    const ull* hbu = (const ull*)(ws + OFF_HBF);
    ull*       hbw = (ull*)(ws + OFF_HBF);
    const float* __restrict__ f0 = (const float*)(ws + OFF_F0);
    const float* __restrict__ o0 = f0 + B_ * H_;
    const float* __restrict__ z0 = o0 + B_ * H_;
    ull*      tcu = (ull*)(ws + OFF_C);
    float*    out_f = out;
    unsigned* bar = (unsigned*)(ws + OFF_BAR);

    // stage V swizzled: chunk j=(g,c,lane) -> V_g[row=cs*16+mm][k=c*32+qq*8..+7]
    const __bf16* Vg = (const __bf16*)(ws + OFF_V);
    for (int j = t; j < 6144; j += 256) {
        int g  = j >> 11;
        int c  = (j >> 6) & 31;
        int ln = j & 63;
        int qq = ln >> 4, mm = ln & 15;
        bf16x8 v = *(const bf16x8*)(Vg + (size_t)g * H_ * H_
                                       + (size_t)(cs * 16 + mm) * H_ + c * 32 + qq * 8);
        *(bf16x8*)(swizzV + (size_t)j * 8) = v;
    }
    __syncthreads();

    const int maxlvl = offsG[N_ + 1];
    const int rid = t & 15;                 // staged pair slot
    const int ck  = t >> 4;                 // 128B chunk within row
    char* stDst = (char*)aSwz + ck * 2048 + rid * 16;
    const char* aB = (const char*)aSwz + lane * 16;
    const __bf16* vbL = swizzV + ((size_t)(wave < 3 ? wave : 0) * 2048 + lane) * 8;

    for (int r = 1; r <= maxlvl; ++r) {
        const int lo = offsG[r], hi = offsG[r + 1];
        const int ntile = (hi - lo + 15) >> 4;
        for (int tt = pg; tt < ntile; tt += 4) {
            const int curTs = lo + (tt << 4);

            // A staging loads: 16x 8B agent-atomic per thread (one 128B chunk)
            int idx = curTs + rid; if (idx > hi - 1) idx = hi - 1;
            int pk = pairsG[idx];
            const ull* src = hbu + ((((size_t)((pk >> 18) * N_ + (pk & 511))) * H_) >> 2)
                                 + (size_t)ck * 16;
            ull u[16];
#pragma unroll
            for (int j = 0; j < 16; ++j) u[j] = AT_LD(src + j);

            // wave3: parent-c prefetch for this tile
            ull pc0 = 0, pc1 = 0;
            if (wave == 3) {
                int idx2 = curTs + (lane >> 2); if (idx2 > hi - 1) idx2 = hi - 1;
                int pk2 = pairsG[idx2];
                const ull* pca = tcu + ((((size_t)((pk2 >> 18) * N_ + (pk2 & 511))) * H_
                                         + cs * 16 + (lane & 3) * 4) >> 1);
                pc0 = AT_LD(pca);
                pc1 = AT_LD(pca + 1);
            }

            __syncthreads();                // S_a: prev tile fully consumed
#pragma unroll
            for (int j = 0; j < 8; ++j) {
                *(ull*)(stDst + j * 256)     = u[2 * j];
                *(ull*)(stDst + j * 256 + 8) = u[2 * j + 1];
            }
            __syncthreads();                // S_b: aSwz visible

            if (wave < 3) {
                floatx4 acc0 = {0.f,0.f,0.f,0.f}, acc1 = {0.f,0.f,0.f,0.f};
                floatx4 acc2 = {0.f,0.f,0.f,0.f}, acc3 = {0.f,0.f,0.f,0.f};
#pragma unroll
                for (int c = 0; c < 32; ++c) {
                    bf16x8 av = *(const bf16x8*)(aB + c * 1024);
                    bf16x8 bv = *(const bf16x8*)(vbL + c * 512);
                    switch (c & 3) {
                    case 0:  acc0 = __builtin_amdgcn_mfma_f32_16x16x32_bf16(av, bv, acc0, 0, 0, 0); break;
                    case 1:  acc1 = __builtin_amdgcn_mfma_f32_16x16x32_bf16(av, bv, acc1, 0, 0, 0); break;
                    case 2:  acc2 = __builtin_amdgcn_mfma_f32_16x16x32_bf16(av, bv, acc2, 0, 0, 0); break;
                    default: acc3 = __builtin_amdgcn_mfma_f32_16x16x32_bf16(av, bv, acc3, 0, 0, 0); break;
                    }
                }
                floatx4 acc = (acc0 + acc1) + (acc2 + acc3);
                ldsC[(wave * 16 + q * 4 + 0) * 17 + m] = acc[0];
                ldsC[(wave * 16 + q * 4 + 1) * 17 + m] = acc[1];
                ldsC[(wave * 16 + q * 4 + 2) * 17 + m] = acc[2];
                ldsC[(wave * 16 + q * 4 + 3) * 17 + m] = acc[3];
            }
            __syncthreads();                // S_c: ldsC ready

            if (wave == 3) {
                int pr = lane >> 2, n0 = (lane & 3) << 2;
                int idx2 = curTs + pr; if (idx2 > hi - 1) idx2 = hi - 1;
                int pk2 = pairsG[idx2];
                int bb = pk2 >> 18, ii = (pk2 >> 9) & 511;
                int hcol0 = cs * 16 + n0;
                floatx4 fv = *(const floatx4*)&f0[bb * H_ + hcol0];
                floatx4 ov = *(const floatx4*)&o0[bb * H_ + hcol0];
                floatx4 zv = *(const floatx4*)&z0[bb * H_ + hcol0];
                union U2 { ull u; float f[2]; };
                U2 w0, w1; w0.u = pc0; w1.u = pc1;
                float pcf[4] = { w0.f[0], w0.f[1], w1.f[0], w1.f[1] };
                floatx4 cc, hv;
                ull hpack = 0;
#pragma unroll
                for (int j = 0; j < 4; ++j) {
                    float af = ldsC[(0 * 16 + pr) * 17 + n0 + j] + fv[j];
                    float ao = ldsC[(1 * 16 + pr) * 17 + n0 + j] + ov[j];
                    float az = ldsC[(2 * 16 + pr) * 17 + n0 + j] + zv[j];
                    float f = 1.0f / (1.0f + __expf(-af));
                    float o = 1.0f / (1.0f + __expf(-ao));
                    float z = tanhf(az);
                    float c = pcf[j] * f + z * (1.0f - f);
                    float h = o * tanhf(c);
                    cc[j] = c; hv[j] = h;
                    hpack |= (ull)__builtin_bit_cast(unsigned short, __float2bfloat16(h)) << (16 * j);
                }
                size_t idxI = ((size_t)(bb * N_ + ii)) * H_ + hcol0;
                U2 c01, c23;
                c01.f[0] = cc[0]; c01.f[1] = cc[1];
                c23.f[0] = cc[2]; c23.f[1] = cc[3];
                AT_ST(tcu + (idxI >> 1),     c01.u);
                AT_ST(tcu + (idxI >> 1) + 1, c23.u);
                *(floatx4*)&out_f[idxI] = hv;
                AT_ST(hbw + (idxI >> 2), hpack);
            }
        }
        if (r < maxlvl) {
            __syncthreads();                // pre-barrier drain (vmcnt0 by compiler)
            if (t == 0) {
                __hip_atomic_fetch_add(bar, 1u, __ATOMIC_RELAXED, __HIP_MEMORY_SCOPE_AGENT);
                unsigned tgt = 256u * (unsigned)r;
                while (__hip_atomic_load(bar, __ATOMIC_RELAXED, __HIP_MEMORY_SCOPE_AGENT) < tgt) {}
            }
            __syncthreads();
        }
    }
}

// ---------------------------------------------------------------------------
extern "C" void kernel_launch(void* const* d_in, const int* in_sizes, int n_in,
                              void* d_out, int out_size, void* d_ws, size_t ws_size,
                              hipStream_t stream)
{
    const float* te  = (const float*)d_in[0];
    const int*  conn = (const int*)d_in[1];
    const float* Wf = (const float*)d_in[3];
    const float* bf = (const float*)d_in[4];
    const float* Wo = (const float*)d_in[5];
    const float* bo = (const float*)d_in[6];
    const float* Wz = (const float*)d_in[7];
    const float* bz = (const float*)d_in[8];
    const float* Tf = (const float*)d_in[9];
    const float* To = (const float*)d_in[10];
    const float* Tz = (const float*)d_in[11];
    float* out = (float*)d_out;
    char*  ws  = (char*)d_ws;

    hipFuncSetAttribute((const void*)scan_kernel,
                        hipFuncAttributeMaxDynamicSharedMemorySize, (int)L_TOT);

    t_transpose<<<dim3(768), dim3(256), 0, stream>>>(Tf, To, Tz, ws);
    k0_root<<<dim3(64), dim3(256), 0, stream>>>(te, Wf, bf, Wo, bo, Wz, bz, out, ws);
    v_gemm<<<dim3(768), dim3(64), 0, stream>>>(ws);
    prep<<<dim3(1), dim3(256), 0, stream>>>(conn, ws);

    void* args[] = { (void*)&out, (void*)&ws };
    hipLaunchCooperativeKernel((const void*)scan_kernel, dim3(256), dim3(256),
                               (void**)args, (unsigned)L_TOT, stream);
}